// Round 12
// baseline (206.224 us; speedup 1.0000x reference)
//
#include <hip/hip_runtime.h>
#include <stdint.h>

#define B_ 4
#define S_ 2048
#define D_ 1024
#define H_ 16
#define A_ 64
#define M_ (B_*S_)    // 8192
#define BH_ (B_*H_)   // 64
#define INV_LN2 1.4426950408889634f

typedef _Float16 f16x8 __attribute__((ext_vector_type(8)));
typedef float    f32x4 __attribute__((ext_vector_type(4)));

__device__ __forceinline__ uint32_t f2h(float f) {
    _Float16 h = (_Float16)f;                      // RNE
    return (uint32_t)__builtin_bit_cast(uint16_t, h);
}

__device__ __forceinline__ float exp2f_fast(float x) {
    return __builtin_amdgcn_exp2f(x);              // v_exp_f32: computes 2^x
}

__device__ __forceinline__ uint32_t pkrtz(float a, float b) {
    return __builtin_bit_cast(uint32_t, __builtin_amdgcn_cvt_pkrtz(a, b));
}

// XOR swizzle for [R][64]-f16 LDS tiles (row stride 128 B)
__device__ __forceinline__ int swz(int row, int col) {
    return (row * 64 + col) ^ ((row & 7) << 3);
}

// ---------------------------------------------------------------- prep: W -> Wt[p][h][a][d] f16
// p==0 (Wq) additionally scaled by 1/ln2 so QK^T scores land in log2 domain.
__global__ __launch_bounds__(256) void prep_w(
    const float* __restrict__ Wq, const float* __restrict__ Wk, const float* __restrict__ Wv,
    uint16_t* __restrict__ Wt)
{
    __shared__ float tile[64][65];
    const int dt = blockIdx.x, h = blockIdx.y, p = blockIdx.z;
    const float* W = (p == 0) ? Wq : (p == 1) ? Wk : Wv;
    const float sc = (p == 0) ? INV_LN2 : 1.0f;
    const float* src = W + (h * D_ + dt * 64) * A_;   // [64 d][64 a]
    const int t = threadIdx.x;
    const int r0 = t >> 4, c4 = (t & 15) * 4;
    #pragma unroll
    for (int i = 0; i < 4; i++) {
        int r = r0 + i * 16;
        float4 x = *(const float4*)(src + r * A_ + c4);
        tile[r][c4] = x.x; tile[r][c4 + 1] = x.y; tile[r][c4 + 2] = x.z; tile[r][c4 + 3] = x.w;
    }
    __syncthreads();
    uint16_t* dst = Wt + (p * H_ + h) * (A_ * D_) + dt * 64;
    #pragma unroll
    for (int i = 0; i < 4; i++) {
        int a = r0 + i * 16;
        int d4 = (t & 15) * 4;
        uint2 o2;
        o2.x = f2h(tile[d4][a] * sc)     | (f2h(tile[d4 + 1][a] * sc) << 16);
        o2.y = f2h(tile[d4 + 2][a] * sc) | (f2h(tile[d4 + 3][a] * sc) << 16);
        *(uint2*)(dst + a * D_ + d4) = o2;
    }
}

// ---------------------------------------------------------------- prep: q/k/v f32 -> f16
__global__ __launch_bounds__(256) void prep_qkv(
    const float* __restrict__ q, const float* __restrict__ k, const float* __restrict__ v,
    uint16_t* __restrict__ qb, uint16_t* __restrict__ kb, uint16_t* __restrict__ vb)
{
    const int gi = blockIdx.x * 256 + threadIdx.x;
    const int NT = M_ * D_ / 8;
    const float* src; uint16_t* dst; int idx;
    if (gi < NT)          { src = q; dst = qb; idx = gi; }
    else if (gi < 2 * NT) { src = k; dst = kb; idx = gi - NT; }
    else                  { src = v; dst = vb; idx = gi - 2 * NT; }
    const int off = idx * 8;
    float4 x0 = *(const float4*)(src + off);
    float4 x1 = *(const float4*)(src + off + 4);
    uint4 o;
    o.x = f2h(x0.x) | (f2h(x0.y) << 16);
    o.y = f2h(x0.z) | (f2h(x0.w) << 16);
    o.z = f2h(x1.x) | (f2h(x1.y) << 16);
    o.w = f2h(x1.z) | (f2h(x1.w) << 16);
    *(uint4*)(dst + off) = o;
}

// ---------------------------------------------------------------- projection GEMM
// 512 thr (8 waves, 2x4), tile M=128 x N=256 (4 heads), K-step 64. f16 A staging
// via global_load_lds with pre-swizzled source columns (48 KB LDS).
__global__ __launch_bounds__(512) void proj_kernel(
    const uint16_t* __restrict__ qb, const uint16_t* __restrict__ kb, const uint16_t* __restrict__ vb,
    const uint16_t* __restrict__ Wt,
    const float* __restrict__ bq, const float* __restrict__ bk, const float* __restrict__ bv,
    uint16_t* __restrict__ qh, uint16_t* __restrict__ kh, uint16_t* __restrict__ vpv)
{
    __shared__ __align__(16) uint16_t As[128 * 64];   // 16 KB
    __shared__ __align__(16) uint16_t Bs[256 * 64];   // 32 KB  rows: h'*64 + a
    const int p = blockIdx.z, nt = blockIdx.y, mt = blockIdx.x;
    const int t = threadIdx.x, lane = t & 63, w = t >> 6;
    const int wr = w >> 2, wc = w & 3;
    const int lr = lane & 15, lg = lane >> 4;
    const int Mbase = mt * 128;
    const uint16_t* Ab = (p == 0) ? qb : (p == 1) ? kb : vb;

    const int arow = t >> 3;
    const int acol = (t * 8) & 63;
    const int ascol = acol ^ ((arow & 7) << 3);
    const uint16_t* asrc0 = Ab + (size_t)(Mbase + arow) * D_ + ascol;
    const uint16_t* asrc1 = asrc0 + (size_t)64 * D_;
    const uint16_t* bsrc[4];
    #pragma unroll
    for (int i = 0; i < 4; i++) {
        int row = arow + i * 64;                 // 0..255: h' = row>>6, a = row&63
        bsrc[i] = Wt + ((size_t)(p * H_ + nt * 4 + (row >> 6)) * A_ + (row & 63)) * D_ + ascol;
    }

    f32x4 acc[4][4] = {};

    for (int kk = 0; kk < D_; kk += 64) {
        __builtin_amdgcn_global_load_lds(asrc0 + kk, &As[w * 512],        16, 0, 0);
        __builtin_amdgcn_global_load_lds(asrc1 + kk, &As[4096 + w * 512], 16, 0, 0);
        #pragma unroll
        for (int i = 0; i < 4; i++)
            __builtin_amdgcn_global_load_lds(bsrc[i] + kk, &Bs[i * 4096 + w * 512], 16, 0, 0);
        __syncthreads();   // drains vmcnt: tiles ready
        #pragma unroll
        for (int kb2 = 0; kb2 < 2; kb2++) {
            f16x8 af[4], bf[4];
            #pragma unroll
            for (int mb = 0; mb < 4; mb++)
                af[mb] = *(const f16x8*)(As + swz(wr * 64 + mb * 16 + lr, kb2 * 32 + 8 * lg));
            #pragma unroll
            for (int nb = 0; nb < 4; nb++)
                bf[nb] = *(const f16x8*)(Bs + swz(wc * 64 + nb * 16 + lr, kb2 * 32 + 8 * lg));
            #pragma unroll
            for (int mb = 0; mb < 4; mb++) {
                #pragma unroll
                for (int nb = 0; nb < 4; nb++)
                    acc[mb][nb] = __builtin_amdgcn_mfma_f32_16x16x32_f16(af[mb], bf[nb], acc[mb][nb], 0, 0, 0);
            }
        }
        __syncthreads();
    }

    const int h = nt * 4 + wc;
    const int b = Mbase >> 11;
    const int bh = b * H_ + h;
    const int sbase = Mbase & (S_ - 1);
    const float* bias = ((p == 0) ? bq : (p == 1) ? bk : bv) + h * A_;
    const float bsc = (p == 0) ? INV_LN2 : 1.0f;
    #pragma unroll
    for (int mb = 0; mb < 4; mb++) {
        #pragma unroll
        for (int nb = 0; nb < 4; nb++) {
            const int a = nb * 16 + lr;
            const float bia = bias[a] * bsc;
            const int s0 = sbase + wr * 64 + mb * 16 + 4 * lg;
            if (p < 2) {
                uint16_t* o = (p == 0) ? qh : kh;
                #pragma unroll
                for (int r = 0; r < 4; r++)
                    o[(bh * S_ + s0 + r) * A_ + a] = (uint16_t)f2h(acc[mb][nb][r] + bia);
            } else {
                const int kt2 = s0 >> 6, kv0 = s0 & 63;
                const int kb2 = kv0 >> 5, jhi = (kv0 >> 4) & 1, lg2 = (kv0 >> 2) & 3;
                uint2 pk2;
                pk2.x = f2h(acc[mb][nb][0] + bia) | (f2h(acc[mb][nb][1] + bia) << 16);
                pk2.y = f2h(acc[mb][nb][2] + bia) | (f2h(acc[mb][nb][3] + bia) << 16);
                *(uint2*)(vpv + ((size_t)((bh * 32 + kt2) * 512 + kb2 * 256 + lg2 * 64 + a)) * 8 + 4 * jhi) = pk2;
            }
        }
    }
}

// ---------------------------------------------------------------- flash attention
// 512 thr / 8 waves, QBLK=128, KVBLK=64 double-buffered (32 KB LDS, reused for the
// output restage). XCD-locality block remap. Swapped QK^T with C-init = -m,
// per-lane defer-check, l-sum via ones-MFMA, pkrtz packing, full-line stores.
__global__ __launch_bounds__(512, 8) void flash_kernel(
    const uint16_t* __restrict__ qh, const uint16_t* __restrict__ kh,
    const uint16_t* __restrict__ vpv, float* __restrict__ out)
{
    __shared__ __align__(16) uint16_t smem[16384];   // K[2]:0..8K | V[2]:16K..32K (bytes)
    const int t = threadIdx.x, lane = t & 63, w = t >> 6;   // w: 0..7
    const int lr = lane & 15, lg = lane >> 4;

    // XCD-locality remap: 16 same-bh blocks land on one XCD's L2
    const int flat = blockIdx.y * gridDim.x + blockIdx.x;   // 0..1023
    const int nf = (flat & 7) * 128 + (flat >> 3);
    const int qt = nf & 15, bh = nf >> 4;
    const int b = bh >> 4, h = bh & (H_ - 1);

    // Q as B-fragment: lane (lr,lg) holds Q[q = qt*128 + w*16 + lr][d = kb*32+8*lg+j]
    f16x8 qf[2];
    {
        const uint16_t* qp = qh + (size_t)(bh * S_ + qt * 128 + w * 16 + lr) * A_ + 8 * lg;
        qf[0] = *(const f16x8*)(qp);
        qf[1] = *(const f16x8*)(qp + 32);
    }
    f16x8 ones;
    #pragma unroll
    for (int j = 0; j < 8; j++) ones[j] = (_Float16)1.0f;

    // Staging: 512 lanes x 16 B = one full 8 KB tile per instruction.
    const int row0 = t >> 3;           // 0..63
    const int col0 = (t * 8) & 63;
    const int scol = col0 ^ ((row0 & 7) << 3);
    const uint16_t* kg = kh + (size_t)(bh * S_ + row0) * A_ + scol;
    const uint16_t* vg = vpv + (size_t)bh * (S_ * A_) + t * 8;

    // negm = -m of q-row lr (log2 domain), all 4 comps equal; feeds QK C-init.
    f32x4 negm = {};
    f32x4 oacc[4] = {};
    f32x4 lsum = {};

    #define STAGE(buf, kt_) do {                                                          \
        __builtin_amdgcn_global_load_lds(kg + (size_t)(kt_) * (64 * A_),                  \
                                         smem + (buf) * 4096 + w * 512, 16, 0, 0);        \
        __builtin_amdgcn_global_load_lds(vg + (size_t)(kt_) * 4096,                       \
                                         smem + 8192 + (buf) * 4096 + w * 512, 16, 0, 0); \
    } while (0)

    const int NT = S_ / 64;   // 32
    STAGE(0, 0);
    __syncthreads();

    for (int kt = 0; kt < NT; kt++) {
        const int cur = kt & 1;
        if (kt + 1 < NT) STAGE(cur ^ 1, kt + 1);
        const uint16_t* Kc = smem + cur * 4096;
        const uint16_t* Vc = smem + 8192 + cur * 4096;

        // QK^T swapped; C-init = negm: sacc[nb] = s(kv = nb*16+4*lg+r, q = lr) - m
        f32x4 sacc[4];
        __builtin_amdgcn_s_setprio(1);
        #pragma unroll
        for (int nb = 0; nb < 4; nb++) {
            f16x8 kf = *(const f16x8*)(Kc + swz(nb * 16 + lr, 8 * lg));
            sacc[nb] = __builtin_amdgcn_mfma_f32_16x16x32_f16(kf, qf[0], negm, 0, 0, 0);
        }
        #pragma unroll
        for (int nb = 0; nb < 4; nb++) {
            f16x8 kf = *(const f16x8*)(Kc + swz(nb * 16 + lr, 32 + 8 * lg));
            sacc[nb] = __builtin_amdgcn_mfma_f32_16x16x32_f16(kf, qf[1], sacc[nb], 0, 0, 0);
        }
        __builtin_amdgcn_s_setprio(0);

        // per-lane max over own 16 scores (no cross-lane reduce on the fast path)
        float a0 = fmaxf(fmaxf(sacc[0][0], sacc[0][1]), sacc[0][2]);
        float a1 = fmaxf(fmaxf(sacc[0][3], sacc[1][0]), sacc[1][1]);
        float a2 = fmaxf(fmaxf(sacc[1][2], sacc[1][3]), sacc[2][0]);
        float a3 = fmaxf(fmaxf(sacc[2][1], sacc[2][2]), sacc[2][3]);
        float a4 = fmaxf(fmaxf(sacc[3][0], sacc[3][1]), sacc[3][2]);
        float pm = fmaxf(fmaxf(fmaxf(a0, a1), fmaxf(a2, a3)), fmaxf(a4, sacc[3][3]));

        // defer-max: rescale only when some row grew past m+11 (P <= 2^11 < f16 max)
        if (__any(pm > 11.0f)) {
            float tm = fmaxf(pm, __shfl_xor(pm, 16));
            tm = fmaxf(tm, __shfl_xor(tm, 32));
            float delta = fmaxf(tm, 0.0f);
            float sc = exp2f_fast(-delta);
            #pragma unroll
            for (int r = 0; r < 4; r++) negm[r] -= delta;
            #pragma unroll
            for (int nb = 0; nb < 4; nb++) {
                #pragma unroll
                for (int r = 0; r < 4; r++) sacc[nb][r] -= delta;
            }
            float scr[4];
            #pragma unroll
            for (int r = 0; r < 4; r++) scr[r] = __shfl(sc, 4 * lg + r);
            #pragma unroll
            for (int r = 0; r < 4; r++) lsum[r] *= scr[r];
            #pragma unroll
            for (int nb = 0; nb < 4; nb++) {
                #pragma unroll
                for (int r = 0; r < 4; r++) oacc[nb][r] *= scr[r];
            }
        }

        // P = exp2(sacc) packed (pkrtz) directly into PV A-fragments
        f16x8 paf[2];
        #pragma unroll
        for (int kb2 = 0; kb2 < 2; kb2++) {
            float e[8];
            #pragma unroll
            for (int jh = 0; jh < 2; jh++) {
                #pragma unroll
                for (int r = 0; r < 4; r++)
                    e[jh * 4 + r] = exp2f_fast(sacc[2 * kb2 + jh][r]);
            }
            uint4 u;
            u.x = pkrtz(e[0], e[1]); u.y = pkrtz(e[2], e[3]);
            u.z = pkrtz(e[4], e[5]); u.w = pkrtz(e[6], e[7]);
            paf[kb2] = __builtin_bit_cast(f16x8, u);
        }

        // l-sum via ones-MFMA (row sums land in oacc row layout) + PV
        __builtin_amdgcn_s_setprio(1);
        lsum = __builtin_amdgcn_mfma_f32_16x16x32_f16(paf[0], ones, lsum, 0, 0, 0);
        lsum = __builtin_amdgcn_mfma_f32_16x16x32_f16(paf[1], ones, lsum, 0, 0, 0);
        #pragma unroll
        for (int kb2 = 0; kb2 < 2; kb2++) {
            #pragma unroll
            for (int nb = 0; nb < 4; nb++) {
                f16x8 vf = *(const f16x8*)(Vc + ((kb2 * 4 + lg) * 64 + nb * 16 + lr) * 8);
                oacc[nb] = __builtin_amdgcn_mfma_f32_16x16x32_f16(paf[kb2], vf, oacc[nb], 0, 0, 0);
            }
        }
        __builtin_amdgcn_s_setprio(0);
        __syncthreads();   // drains vmcnt (next buf ready) + all waves done with cur buf
    }
    #undef STAGE

    // normalize into LDS (reusing K/V space), then full-line coalesced stores
    float* outs = (float*)smem;   // 128 x 64 f32 = 32 KB
    #pragma unroll
    for (int r = 0; r < 4; r++) {
        const float inv = 1.0f / lsum[r];
        const int sl = w * 16 + 4 * lg + r;
        #pragma unroll
        for (int nb = 0; nb < 4; nb++)
            outs[sl * 64 + nb * 16 + lr] = oacc[nb][r] * inv;
    }
    __syncthreads();
    const int orow = t >> 4, oslot = t & 15;
    float* obase = out + (size_t)(b * S_ + qt * 128 + orow) * (H_ * A_) + h * A_ + oslot * 4;
    #pragma unroll
    for (int i = 0; i < 4; i++)
        *(float4*)(obase + (size_t)(32 * i) * (H_ * A_)) =
            *(const float4*)(outs + (orow + 32 * i) * 64 + oslot * 4);
}

// ----------------------------------------------------------------
extern "C" void kernel_launch(void* const* d_in, const int* in_sizes, int n_in,
                              void* d_out, int out_size, void* d_ws, size_t ws_size,
                              hipStream_t stream)
{
    const float* q  = (const float*)d_in[0];
    const float* k  = (const float*)d_in[1];
    const float* v  = (const float*)d_in[2];
    const float* Wq = (const float*)d_in[3];
    const float* bq = (const float*)d_in[4];
    const float* Wk = (const float*)d_in[5];
    const float* bk = (const float*)d_in[6];
    const float* Wv = (const float*)d_in[7];
    const float* bv = (const float*)d_in[8];
    float* out = (float*)d_out;

    uint8_t* ws = (uint8_t*)d_ws;
    const size_t SZ_H  = (size_t)BH_ * S_ * A_ * 2;     // 16 MB each
    const size_t SZ_WT = (size_t)3 * H_ * A_ * D_ * 2;  // 6 MB
    const size_t SZ_AB = (size_t)M_ * D_ * 2;           // 16 MB each
    uint16_t* qh  = (uint16_t*)(ws);
    uint16_t* kh  = (uint16_t*)(ws + SZ_H);
    uint16_t* vpv = (uint16_t*)(ws + 2 * SZ_H);
    uint16_t* Wt  = (uint16_t*)(ws + 3 * SZ_H);
    uint16_t* qb  = (uint16_t*)(ws + 3 * SZ_H + SZ_WT);
    uint16_t* kb  = (uint16_t*)(ws + 3 * SZ_H + SZ_WT + SZ_AB);
    uint16_t* vb  = (uint16_t*)(ws + 3 * SZ_H + SZ_WT + 2 * SZ_AB);

    prep_w<<<dim3(16, H_, 3), 256, 0, stream>>>(Wq, Wk, Wv, Wt);
    prep_qkv<<<dim3(3 * M_ * D_ / 8 / 256), 256, 0, stream>>>(q, k, v, qb, kb, vb);
    proj_kernel<<<dim3(M_ / 128, 4, 3), 512, 0, stream>>>(qb, kb, vb, Wt,
                                                          bq, bk, bv, qh, kh, vpv);
    flash_kernel<<<dim3(S_ / 128, BH_), 512, 0, stream>>>(qh, kh, vpv, out);
}

// Round 13
// 191.828 us; speedup vs baseline: 1.0750x; 1.0750x over previous
//
#include <hip/hip_runtime.h>
#include <stdint.h>

#define B_ 4
#define S_ 2048
#define D_ 1024
#define H_ 16
#define A_ 64
#define M_ (B_*S_)    // 8192
#define BH_ (B_*H_)   // 64
#define INV_LN2 1.4426950408889634f

typedef _Float16 f16x8 __attribute__((ext_vector_type(8)));
typedef float    f32x4 __attribute__((ext_vector_type(4)));

__device__ __forceinline__ uint32_t f2h(float f) {
    _Float16 h = (_Float16)f;                      // RNE
    return (uint32_t)__builtin_bit_cast(uint16_t, h);
}

__device__ __forceinline__ float exp2f_fast(float x) {
    return __builtin_amdgcn_exp2f(x);              // v_exp_f32: computes 2^x
}

__device__ __forceinline__ uint32_t pkrtz(float a, float b) {
    return __builtin_bit_cast(uint32_t, __builtin_amdgcn_cvt_pkrtz(a, b));
}

// XOR swizzle for [R][64]-f16 LDS tiles (row stride 128 B)
__device__ __forceinline__ int swz(int row, int col) {
    return (row * 64 + col) ^ ((row & 7) << 3);
}

// ---------------------------------------------------------------- prep: W -> Wt[p][h][a][d] f16
// p==0 (Wq) additionally scaled by 1/ln2 so QK^T scores land in log2 domain.
__global__ __launch_bounds__(256) void prep_w(
    const float* __restrict__ Wq, const float* __restrict__ Wk, const float* __restrict__ Wv,
    uint16_t* __restrict__ Wt)
{
    __shared__ float tile[64][65];
    const int dt = blockIdx.x, h = blockIdx.y, p = blockIdx.z;
    const float* W = (p == 0) ? Wq : (p == 1) ? Wk : Wv;
    const float sc = (p == 0) ? INV_LN2 : 1.0f;
    const float* src = W + (h * D_ + dt * 64) * A_;   // [64 d][64 a]
    const int t = threadIdx.x;
    const int r0 = t >> 4, c4 = (t & 15) * 4;
    #pragma unroll
    for (int i = 0; i < 4; i++) {
        int r = r0 + i * 16;
        float4 x = *(const float4*)(src + r * A_ + c4);
        tile[r][c4] = x.x; tile[r][c4 + 1] = x.y; tile[r][c4 + 2] = x.z; tile[r][c4 + 3] = x.w;
    }
    __syncthreads();
    uint16_t* dst = Wt + (p * H_ + h) * (A_ * D_) + dt * 64;
    #pragma unroll
    for (int i = 0; i < 4; i++) {
        int a = r0 + i * 16;
        int d4 = (t & 15) * 4;
        uint2 o2;
        o2.x = f2h(tile[d4][a] * sc)     | (f2h(tile[d4 + 1][a] * sc) << 16);
        o2.y = f2h(tile[d4 + 2][a] * sc) | (f2h(tile[d4 + 3][a] * sc) << 16);
        *(uint2*)(dst + a * D_ + d4) = o2;
    }
}

// ---------------------------------------------------------------- projection GEMM (fused f32 A, BK=32)
// 512 thr (8 waves, 2x4), tile M=128 x N=256 (4 heads), K-step 32, LDS 32 KB.
// A staged as RAW f32 via global_load_lds; fragments convert f32->f16 with pkrtz.
// A-tile [128][32] f32 (8x16B slots/row):  phys = logical ^ (row&7)
// B-tile [256][32] f16 (4x16B slots/row):  phys = logical ^ ((row>>1)&3)
// Both XORs invariant under the staging row step (A: +64, B: +128).
__global__ __launch_bounds__(512) void proj_kernel(
    const float* __restrict__ qsrc, const float* __restrict__ ksrc, const float* __restrict__ vsrc,
    const uint16_t* __restrict__ Wt,
    const float* __restrict__ bq, const float* __restrict__ bk, const float* __restrict__ bv,
    uint16_t* __restrict__ qh, uint16_t* __restrict__ kh, uint16_t* __restrict__ vpv)
{
    __shared__ __align__(16) float    Asf[128 * 32];  // 16 KB
    __shared__ __align__(16) uint16_t Bs[256 * 32];   // 16 KB   rows: h'*64 + a
    const int p = blockIdx.z, nt = blockIdx.y, mt = blockIdx.x;
    const int t = threadIdx.x, lane = t & 63, w = t >> 6;
    const int wr = w >> 2, wc = w & 3;
    const int lr = lane & 15, lg = lane >> 4;
    const int Mbase = mt * 128;
    const float* Af = (p == 0) ? qsrc : (p == 1) ? ksrc : vsrc;

    // A staging: lane t -> row (t>>3)+64i, phys slot t&7 sources logical (t&7)^(row&7)
    const int ar = t >> 3;                       // 0..63
    const int asl = (t & 7) ^ (ar & 7);
    const float* asrc = Af + (size_t)(Mbase + ar) * D_ + asl * 4;

    // B staging: lane t -> row (t>>2)+128i, phys slot t&3 sources logical (t&3)^((row>>1)&3)
    const int br = t >> 2;                       // 0..127
    const int bsl = (t & 3) ^ ((br >> 1) & 3);
    const uint16_t* bsrc[2];
    #pragma unroll
    for (int i = 0; i < 2; i++) {
        int row = br + 128 * i;                  // 0..255: h' = row>>6, a = row&63
        bsrc[i] = Wt + ((size_t)(p * H_ + nt * 4 + (row >> 6)) * A_ + (row & 63)) * D_ + bsl * 8;
    }

    f32x4 acc[4][4] = {};

    for (int kk = 0; kk < D_; kk += 32) {
        __builtin_amdgcn_global_load_lds(asrc + kk,                  (char*)Asf + w * 1024,        16, 0, 0);
        __builtin_amdgcn_global_load_lds(asrc + kk + (size_t)64 * D_,(char*)Asf + 8192 + w * 1024, 16, 0, 0);
        __builtin_amdgcn_global_load_lds(bsrc[0] + kk, (char*)Bs + w * 1024,        16, 0, 0);
        __builtin_amdgcn_global_load_lds(bsrc[1] + kk, (char*)Bs + 8192 + w * 1024, 16, 0, 0);
        __syncthreads();   // drains vmcnt: tiles ready

        f16x8 af[4], bf[4];
        #pragma unroll
        for (int mb = 0; mb < 4; mb++) {
            const int r = wr * 64 + mb * 16 + lr;
            const int c = r & 7;
            const float* base = Asf + r * 32;
            f32x4 lo = *(const f32x4*)(base + (((2 * lg)     ^ c) << 2));
            f32x4 hi = *(const f32x4*)(base + (((2 * lg + 1) ^ c) << 2));
            uint4 u;
            u.x = pkrtz(lo[0], lo[1]); u.y = pkrtz(lo[2], lo[3]);
            u.z = pkrtz(hi[0], hi[1]); u.w = pkrtz(hi[2], hi[3]);
            af[mb] = __builtin_bit_cast(f16x8, u);
        }
        #pragma unroll
        for (int nb = 0; nb < 4; nb++) {
            const int r = wc * 64 + nb * 16 + lr;
            const int ph = lg ^ ((r >> 1) & 3);
            bf[nb] = *(const f16x8*)(Bs + r * 32 + ph * 8);
        }
        #pragma unroll
        for (int mb = 0; mb < 4; mb++) {
            #pragma unroll
            for (int nb = 0; nb < 4; nb++)
                acc[mb][nb] = __builtin_amdgcn_mfma_f32_16x16x32_f16(af[mb], bf[nb], acc[mb][nb], 0, 0, 0);
        }
        __syncthreads();   // all waves done reading before next stage
    }

    const int h = nt * 4 + wc;
    const int b = Mbase >> 11;
    const int bh = b * H_ + h;
    const int sbase = Mbase & (S_ - 1);
    const float* bias = ((p == 0) ? bq : (p == 1) ? bk : bv) + h * A_;
    const float bsc = (p == 0) ? INV_LN2 : 1.0f;
    #pragma unroll
    for (int mb = 0; mb < 4; mb++) {
        #pragma unroll
        for (int nb = 0; nb < 4; nb++) {
            const int a = nb * 16 + lr;
            const float bia = bias[a] * bsc;
            const int s0 = sbase + wr * 64 + mb * 16 + 4 * lg;
            if (p < 2) {
                uint16_t* o = (p == 0) ? qh : kh;
                #pragma unroll
                for (int r = 0; r < 4; r++)
                    o[(bh * S_ + s0 + r) * A_ + a] = (uint16_t)f2h(acc[mb][nb][r] + bia);
            } else {
                const int kt2 = s0 >> 6, kv0 = s0 & 63;
                const int kb2 = kv0 >> 5, jhi = (kv0 >> 4) & 1, lg2 = (kv0 >> 2) & 3;
                uint2 pk2;
                pk2.x = f2h(acc[mb][nb][0] + bia) | (f2h(acc[mb][nb][1] + bia) << 16);
                pk2.y = f2h(acc[mb][nb][2] + bia) | (f2h(acc[mb][nb][3] + bia) << 16);
                *(uint2*)(vpv + ((size_t)((bh * 32 + kt2) * 512 + kb2 * 256 + lg2 * 64 + a)) * 8 + 4 * jhi) = pk2;
            }
        }
    }
}

// ---------------------------------------------------------------- flash attention
// 512 thr / 8 waves, QBLK=128, KVBLK=64 double-buffered (32 KB LDS, reused for the
// output restage). XCD-locality block remap. Swapped QK^T with C-init = -m,
// per-lane defer-check, l-sum via ones-MFMA, pkrtz packing, full-line stores.
__global__ __launch_bounds__(512, 8) void flash_kernel(
    const uint16_t* __restrict__ qh, const uint16_t* __restrict__ kh,
    const uint16_t* __restrict__ vpv, float* __restrict__ out)
{
    __shared__ __align__(16) uint16_t smem[16384];   // K[2]:0..8K | V[2]:16K..32K (bytes)
    const int t = threadIdx.x, lane = t & 63, w = t >> 6;   // w: 0..7
    const int lr = lane & 15, lg = lane >> 4;

    // XCD-locality remap: 16 same-bh blocks land on one XCD's L2
    const int flat = blockIdx.y * gridDim.x + blockIdx.x;   // 0..1023
    const int nf = (flat & 7) * 128 + (flat >> 3);
    const int qt = nf & 15, bh = nf >> 4;
    const int b = bh >> 4, h = bh & (H_ - 1);

    // Q as B-fragment: lane (lr,lg) holds Q[q = qt*128 + w*16 + lr][d = kb*32+8*lg+j]
    f16x8 qf[2];
    {
        const uint16_t* qp = qh + (size_t)(bh * S_ + qt * 128 + w * 16 + lr) * A_ + 8 * lg;
        qf[0] = *(const f16x8*)(qp);
        qf[1] = *(const f16x8*)(qp + 32);
    }
    f16x8 ones;
    #pragma unroll
    for (int j = 0; j < 8; j++) ones[j] = (_Float16)1.0f;

    // Staging: 512 lanes x 16 B = one full 8 KB tile per instruction.
    const int row0 = t >> 3;           // 0..63
    const int col0 = (t * 8) & 63;
    const int scol = col0 ^ ((row0 & 7) << 3);
    const uint16_t* kg = kh + (size_t)(bh * S_ + row0) * A_ + scol;
    const uint16_t* vg = vpv + (size_t)bh * (S_ * A_) + t * 8;

    // negm = -m of q-row lr (log2 domain), all 4 comps equal; feeds QK C-init.
    f32x4 negm = {};
    f32x4 oacc[4] = {};
    f32x4 lsum = {};

    #define STAGE(buf, kt_) do {                                                          \
        __builtin_amdgcn_global_load_lds(kg + (size_t)(kt_) * (64 * A_),                  \
                                         smem + (buf) * 4096 + w * 512, 16, 0, 0);        \
        __builtin_amdgcn_global_load_lds(vg + (size_t)(kt_) * 4096,                       \
                                         smem + 8192 + (buf) * 4096 + w * 512, 16, 0, 0); \
    } while (0)

    const int NT = S_ / 64;   // 32
    STAGE(0, 0);
    __syncthreads();

    for (int kt = 0; kt < NT; kt++) {
        const int cur = kt & 1;
        if (kt + 1 < NT) STAGE(cur ^ 1, kt + 1);
        const uint16_t* Kc = smem + cur * 4096;
        const uint16_t* Vc = smem + 8192 + cur * 4096;

        // QK^T swapped; C-init = negm: sacc[nb] = s(kv = nb*16+4*lg+r, q = lr) - m
        f32x4 sacc[4];
        __builtin_amdgcn_s_setprio(1);
        #pragma unroll
        for (int nb = 0; nb < 4; nb++) {
            f16x8 kf = *(const f16x8*)(Kc + swz(nb * 16 + lr, 8 * lg));
            sacc[nb] = __builtin_amdgcn_mfma_f32_16x16x32_f16(kf, qf[0], negm, 0, 0, 0);
        }
        #pragma unroll
        for (int nb = 0; nb < 4; nb++) {
            f16x8 kf = *(const f16x8*)(Kc + swz(nb * 16 + lr, 32 + 8 * lg));
            sacc[nb] = __builtin_amdgcn_mfma_f32_16x16x32_f16(kf, qf[1], sacc[nb], 0, 0, 0);
        }
        __builtin_amdgcn_s_setprio(0);

        // per-lane max over own 16 scores (no cross-lane reduce on the fast path)
        float a0 = fmaxf(fmaxf(sacc[0][0], sacc[0][1]), sacc[0][2]);
        float a1 = fmaxf(fmaxf(sacc[0][3], sacc[1][0]), sacc[1][1]);
        float a2 = fmaxf(fmaxf(sacc[1][2], sacc[1][3]), sacc[2][0]);
        float a3 = fmaxf(fmaxf(sacc[2][1], sacc[2][2]), sacc[2][3]);
        float a4 = fmaxf(fmaxf(sacc[3][0], sacc[3][1]), sacc[3][2]);
        float pm = fmaxf(fmaxf(fmaxf(a0, a1), fmaxf(a2, a3)), fmaxf(a4, sacc[3][3]));

        // defer-max: rescale only when some row grew past m+11 (P <= 2^11 < f16 max)
        if (__any(pm > 11.0f)) {
            float tm = fmaxf(pm, __shfl_xor(pm, 16));
            tm = fmaxf(tm, __shfl_xor(tm, 32));
            float delta = fmaxf(tm, 0.0f);
            float sc = exp2f_fast(-delta);
            #pragma unroll
            for (int r = 0; r < 4; r++) negm[r] -= delta;
            #pragma unroll
            for (int nb = 0; nb < 4; nb++) {
                #pragma unroll
                for (int r = 0; r < 4; r++) sacc[nb][r] -= delta;
            }
            float scr[4];
            #pragma unroll
            for (int r = 0; r < 4; r++) scr[r] = __shfl(sc, 4 * lg + r);
            #pragma unroll
            for (int r = 0; r < 4; r++) lsum[r] *= scr[r];
            #pragma unroll
            for (int nb = 0; nb < 4; nb++) {
                #pragma unroll
                for (int r = 0; r < 4; r++) oacc[nb][r] *= scr[r];
            }
        }

        // P = exp2(sacc) packed (pkrtz) directly into PV A-fragments
        f16x8 paf[2];
        #pragma unroll
        for (int kb2 = 0; kb2 < 2; kb2++) {
            float e[8];
            #pragma unroll
            for (int jh = 0; jh < 2; jh++) {
                #pragma unroll
                for (int r = 0; r < 4; r++)
                    e[jh * 4 + r] = exp2f_fast(sacc[2 * kb2 + jh][r]);
            }
            uint4 u;
            u.x = pkrtz(e[0], e[1]); u.y = pkrtz(e[2], e[3]);
            u.z = pkrtz(e[4], e[5]); u.w = pkrtz(e[6], e[7]);
            paf[kb2] = __builtin_bit_cast(f16x8, u);
        }

        // l-sum via ones-MFMA (row sums land in oacc row layout) + PV
        __builtin_amdgcn_s_setprio(1);
        lsum = __builtin_amdgcn_mfma_f32_16x16x32_f16(paf[0], ones, lsum, 0, 0, 0);
        lsum = __builtin_amdgcn_mfma_f32_16x16x32_f16(paf[1], ones, lsum, 0, 0, 0);
        #pragma unroll
        for (int kb2 = 0; kb2 < 2; kb2++) {
            #pragma unroll
            for (int nb = 0; nb < 4; nb++) {
                f16x8 vf = *(const f16x8*)(Vc + ((kb2 * 4 + lg) * 64 + nb * 16 + lr) * 8);
                oacc[nb] = __builtin_amdgcn_mfma_f32_16x16x32_f16(paf[kb2], vf, oacc[nb], 0, 0, 0);
            }
        }
        __builtin_amdgcn_s_setprio(0);
        __syncthreads();   // drains vmcnt (next buf ready) + all waves done with cur buf
    }
    #undef STAGE

    // normalize into LDS (reusing K/V space), then full-line coalesced stores
    float* outs = (float*)smem;   // 128 x 64 f32 = 32 KB
    #pragma unroll
    for (int r = 0; r < 4; r++) {
        const float inv = 1.0f / lsum[r];
        const int sl = w * 16 + 4 * lg + r;
        #pragma unroll
        for (int nb = 0; nb < 4; nb++)
            outs[sl * 64 + nb * 16 + lr] = oacc[nb][r] * inv;
    }
    __syncthreads();
    const int orow = t >> 4, oslot = t & 15;
    float* obase = out + (size_t)(b * S_ + qt * 128 + orow) * (H_ * A_) + h * A_ + oslot * 4;
    #pragma unroll
    for (int i = 0; i < 4; i++)
        *(float4*)(obase + (size_t)(32 * i) * (H_ * A_)) =
            *(const float4*)(outs + (orow + 32 * i) * 64 + oslot * 4);
}

// ----------------------------------------------------------------
extern "C" void kernel_launch(void* const* d_in, const int* in_sizes, int n_in,
                              void* d_out, int out_size, void* d_ws, size_t ws_size,
                              hipStream_t stream)
{
    const float* q  = (const float*)d_in[0];
    const float* k  = (const float*)d_in[1];
    const float* v  = (const float*)d_in[2];
    const float* Wq = (const float*)d_in[3];
    const float* bq = (const float*)d_in[4];
    const float* Wk = (const float*)d_in[5];
    const float* bk = (const float*)d_in[6];
    const float* Wv = (const float*)d_in[7];
    const float* bv = (const float*)d_in[8];
    float* out = (float*)d_out;

    uint8_t* ws = (uint8_t*)d_ws;
    const size_t SZ_H  = (size_t)BH_ * S_ * A_ * 2;     // 16 MB each
    uint16_t* qh  = (uint16_t*)(ws);
    uint16_t* kh  = (uint16_t*)(ws + SZ_H);
    uint16_t* vpv = (uint16_t*)(ws + 2 * SZ_H);
    uint16_t* Wt  = (uint16_t*)(ws + 3 * SZ_H);

    prep_w<<<dim3(16, H_, 3), 256, 0, stream>>>(Wq, Wk, Wv, Wt);
    proj_kernel<<<dim3(M_ / 128, 4, 3), 512, 0, stream>>>(q, k, v, Wt,
                                                          bq, bk, bv, qh, kh, vpv);
    flash_kernel<<<dim3(S_ / 128, BH_), 512, 0, stream>>>(qh, kh, vpv, out);
}

// Round 14
// 170.644 us; speedup vs baseline: 1.2085x; 1.1241x over previous
//
#include <hip/hip_runtime.h>
#include <stdint.h>

#define B_ 4
#define S_ 2048
#define D_ 1024
#define H_ 16
#define A_ 64
#define M_ (B_*S_)    // 8192
#define BH_ (B_*H_)   // 64
#define INV_LN2 1.4426950408889634f

typedef _Float16 f16x8 __attribute__((ext_vector_type(8)));
typedef float    f32x4 __attribute__((ext_vector_type(4)));

__device__ __forceinline__ uint32_t f2h(float f) {
    _Float16 h = (_Float16)f;                      // RNE
    return (uint32_t)__builtin_bit_cast(uint16_t, h);
}

__device__ __forceinline__ float exp2f_fast(float x) {
    return __builtin_amdgcn_exp2f(x);              // v_exp_f32: computes 2^x
}

__device__ __forceinline__ uint32_t pkrtz(float a, float b) {
    return __builtin_bit_cast(uint32_t, __builtin_amdgcn_cvt_pkrtz(a, b));
}

// XOR swizzle for [R][64]-f16 LDS tiles (row stride 128 B)
__device__ __forceinline__ int swz(int row, int col) {
    return (row * 64 + col) ^ ((row & 7) << 3);
}

// ---------------------------------------------------------------- prep: W -> Wt[p][h][a][d] f16
// p==0 (Wq) additionally scaled by 1/ln2 so QK^T scores land in log2 domain.
__global__ __launch_bounds__(256) void prep_w(
    const float* __restrict__ Wq, const float* __restrict__ Wk, const float* __restrict__ Wv,
    uint16_t* __restrict__ Wt)
{
    __shared__ float tile[64][65];
    const int dt = blockIdx.x, h = blockIdx.y, p = blockIdx.z;
    const float* W = (p == 0) ? Wq : (p == 1) ? Wk : Wv;
    const float sc = (p == 0) ? INV_LN2 : 1.0f;
    const float* src = W + (h * D_ + dt * 64) * A_;   // [64 d][64 a]
    const int t = threadIdx.x;
    const int r0 = t >> 4, c4 = (t & 15) * 4;
    #pragma unroll
    for (int i = 0; i < 4; i++) {
        int r = r0 + i * 16;
        float4 x = *(const float4*)(src + r * A_ + c4);
        tile[r][c4] = x.x; tile[r][c4 + 1] = x.y; tile[r][c4 + 2] = x.z; tile[r][c4 + 3] = x.w;
    }
    __syncthreads();
    uint16_t* dst = Wt + (p * H_ + h) * (A_ * D_) + dt * 64;
    #pragma unroll
    for (int i = 0; i < 4; i++) {
        int a = r0 + i * 16;
        int d4 = (t & 15) * 4;
        uint2 o2;
        o2.x = f2h(tile[d4][a] * sc)     | (f2h(tile[d4 + 1][a] * sc) << 16);
        o2.y = f2h(tile[d4 + 2][a] * sc) | (f2h(tile[d4 + 3][a] * sc) << 16);
        *(uint2*)(dst + a * D_ + d4) = o2;
    }
}

// ---------------------------------------------------------------- projection GEMM (fused f32 A, BK=32, 2-deep)
// 512 thr (8 waves, 2x4), tile M=128 x N=256 (4 heads), K-step 32.
// Double-buffered LDS (64 KB) with counted vmcnt: stage(t+1) issued before
// waiting vmcnt(4) for stage(t) — loads get a full compute phase of latency cover.
__global__ __launch_bounds__(512) void proj_kernel(
    const float* __restrict__ qsrc, const float* __restrict__ ksrc, const float* __restrict__ vsrc,
    const uint16_t* __restrict__ Wt,
    const float* __restrict__ bq, const float* __restrict__ bk, const float* __restrict__ bv,
    uint16_t* __restrict__ qh, uint16_t* __restrict__ kh, uint16_t* __restrict__ vpv)
{
    __shared__ __align__(16) float    Asf[2][128 * 32];  // 2 x 16 KB
    __shared__ __align__(16) uint16_t Bs[2][256 * 32];   // 2 x 16 KB   rows: h'*64 + a
    const int p = blockIdx.z, nt = blockIdx.y, mt = blockIdx.x;
    const int t = threadIdx.x, lane = t & 63, w = t >> 6;
    const int wr = w >> 2, wc = w & 3;
    const int lr = lane & 15, lg = lane >> 4;
    const int Mbase = mt * 128;
    const float* Af = (p == 0) ? qsrc : (p == 1) ? ksrc : vsrc;

    // A staging: lane t -> row (t>>3)+64i, phys slot t&7 sources logical (t&7)^(row&7)
    const int ar = t >> 3;                       // 0..63
    const int asl = (t & 7) ^ (ar & 7);
    const float* asrc = Af + (size_t)(Mbase + ar) * D_ + asl * 4;

    // B staging: lane t -> row (t>>2)+128i, phys slot t&3 sources logical (t&3)^((row>>1)&3)
    const int br = t >> 2;                       // 0..127
    const int bsl = (t & 3) ^ ((br >> 1) & 3);
    const uint16_t* bsrc[2];
    #pragma unroll
    for (int i = 0; i < 2; i++) {
        int row = br + 128 * i;                  // 0..255: h' = row>>6, a = row&63
        bsrc[i] = Wt + ((size_t)(p * H_ + nt * 4 + (row >> 6)) * A_ + (row & 63)) * D_ + bsl * 8;
    }

    f32x4 acc[4][4] = {};

    #define PSTAGE(buf, kkv) do {                                                                  \
        __builtin_amdgcn_global_load_lds(asrc + (kkv),                                             \
                                         (char*)(&Asf[buf][0]) + w * 1024,        16, 0, 0);       \
        __builtin_amdgcn_global_load_lds(asrc + (kkv) + (size_t)64 * D_,                           \
                                         (char*)(&Asf[buf][0]) + 8192 + w * 1024, 16, 0, 0);       \
        __builtin_amdgcn_global_load_lds(bsrc[0] + (kkv),                                          \
                                         (char*)(&Bs[buf][0]) + w * 1024,         16, 0, 0);       \
        __builtin_amdgcn_global_load_lds(bsrc[1] + (kkv),                                          \
                                         (char*)(&Bs[buf][0]) + 8192 + w * 1024,  16, 0, 0);       \
    } while (0)

    const int NKS = D_ / 32;   // 32
    PSTAGE(0, 0);

    for (int ks = 0; ks < NKS; ks++) {
        const int cur = ks & 1;
        if (ks + 1 < NKS) {
            PSTAGE(cur ^ 1, (ks + 1) * 32);
            asm volatile("s_waitcnt vmcnt(4)" ::: "memory");   // stage(ks) landed; (ks+1) in flight
        } else {
            asm volatile("s_waitcnt vmcnt(0)" ::: "memory");
        }
        __builtin_amdgcn_s_barrier();
        __builtin_amdgcn_sched_barrier(0);

        f16x8 af[4], bf[4];
        #pragma unroll
        for (int mb = 0; mb < 4; mb++) {
            const int r = wr * 64 + mb * 16 + lr;
            const int c = r & 7;
            const float* base = &Asf[cur][0] + r * 32;
            f32x4 lo = *(const f32x4*)(base + (((2 * lg)     ^ c) << 2));
            f32x4 hi = *(const f32x4*)(base + (((2 * lg + 1) ^ c) << 2));
            uint4 u;
            u.x = pkrtz(lo[0], lo[1]); u.y = pkrtz(lo[2], lo[3]);
            u.z = pkrtz(hi[0], hi[1]); u.w = pkrtz(hi[2], hi[3]);
            af[mb] = __builtin_bit_cast(f16x8, u);
        }
        #pragma unroll
        for (int nb = 0; nb < 4; nb++) {
            const int r = wc * 64 + nb * 16 + lr;
            const int ph = lg ^ ((r >> 1) & 3);
            bf[nb] = *(const f16x8*)(&Bs[cur][0] + r * 32 + ph * 8);
        }
        #pragma unroll
        for (int mb = 0; mb < 4; mb++) {
            #pragma unroll
            for (int nb = 0; nb < 4; nb++)
                acc[mb][nb] = __builtin_amdgcn_mfma_f32_16x16x32_f16(af[mb], bf[nb], acc[mb][nb], 0, 0, 0);
        }
        __builtin_amdgcn_s_barrier();          // all waves done reading buf cur (overwritten at ks+2)
        __builtin_amdgcn_sched_barrier(0);
    }
    #undef PSTAGE

    const int h = nt * 4 + wc;
    const int b = Mbase >> 11;
    const int bh = b * H_ + h;
    const int sbase = Mbase & (S_ - 1);
    const float* bias = ((p == 0) ? bq : (p == 1) ? bk : bv) + h * A_;
    const float bsc = (p == 0) ? INV_LN2 : 1.0f;
    #pragma unroll
    for (int mb = 0; mb < 4; mb++) {
        #pragma unroll
        for (int nb = 0; nb < 4; nb++) {
            const int a = nb * 16 + lr;
            const float bia = bias[a] * bsc;
            const int s0 = sbase + wr * 64 + mb * 16 + 4 * lg;
            if (p < 2) {
                uint16_t* o = (p == 0) ? qh : kh;
                #pragma unroll
                for (int r = 0; r < 4; r++)
                    o[(bh * S_ + s0 + r) * A_ + a] = (uint16_t)f2h(acc[mb][nb][r] + bia);
            } else {
                const int kt2 = s0 >> 6, kv0 = s0 & 63;
                const int kb2 = kv0 >> 5, jhi = (kv0 >> 4) & 1, lg2 = (kv0 >> 2) & 3;
                uint2 pk2;
                pk2.x = f2h(acc[mb][nb][0] + bia) | (f2h(acc[mb][nb][1] + bia) << 16);
                pk2.y = f2h(acc[mb][nb][2] + bia) | (f2h(acc[mb][nb][3] + bia) << 16);
                *(uint2*)(vpv + ((size_t)((bh * 32 + kt2) * 512 + kb2 * 256 + lg2 * 64 + a)) * 8 + 4 * jhi) = pk2;
            }
        }
    }
}

// ---------------------------------------------------------------- flash attention
// 512 thr / 8 waves, QBLK=128, KVBLK=64, 3-deep rotating K/V (48 KB) with counted
// vmcnt(2) and ONE raw barrier per tile (never drain in the main loop). XCD remap,
// swapped QK^T with C-init = -m, per-lane defer-check, l-sum via ones-MFMA,
// pkrtz packing, full-line stores via LDS restage.
__global__ __launch_bounds__(512, 8) void flash_kernel(
    const uint16_t* __restrict__ qh, const uint16_t* __restrict__ kh,
    const uint16_t* __restrict__ vpv, float* __restrict__ out)
{
    __shared__ __align__(16) uint16_t smem[24576];   // K[3]: 0..12287 | V[3]: 12288..24575 (u16)
    const int t = threadIdx.x, lane = t & 63, w = t >> 6;   // w: 0..7
    const int lr = lane & 15, lg = lane >> 4;

    // XCD-locality remap: 16 same-bh blocks land on one XCD's L2
    const int flat = blockIdx.y * gridDim.x + blockIdx.x;   // 0..1023
    const int nf = (flat & 7) * 128 + (flat >> 3);
    const int qt = nf & 15, bh = nf >> 4;
    const int b = bh >> 4, h = bh & (H_ - 1);

    // Q as B-fragment: lane (lr,lg) holds Q[q = qt*128 + w*16 + lr][d = kb*32+8*lg+j]
    f16x8 qf[2];
    {
        const uint16_t* qp = qh + (size_t)(bh * S_ + qt * 128 + w * 16 + lr) * A_ + 8 * lg;
        qf[0] = *(const f16x8*)(qp);
        qf[1] = *(const f16x8*)(qp + 32);
    }
    f16x8 ones;
    #pragma unroll
    for (int j = 0; j < 8; j++) ones[j] = (_Float16)1.0f;

    // Staging: 512 lanes x 16 B = one full 8 KB tile per instruction.
    const int row0 = t >> 3;           // 0..63
    const int col0 = (t * 8) & 63;
    const int scol = col0 ^ ((row0 & 7) << 3);
    const uint16_t* kg = kh + (size_t)(bh * S_ + row0) * A_ + scol;
    const uint16_t* vg = vpv + (size_t)bh * (S_ * A_) + t * 8;

    // negm = -m of q-row lr (log2 domain), all 4 comps equal; feeds QK C-init.
    f32x4 negm = {};
    f32x4 oacc[4] = {};
    f32x4 lsum = {};

    #define FSTAGE(buf, kt_) do {                                                         \
        __builtin_amdgcn_global_load_lds(kg + (size_t)(kt_) * (64 * A_),                  \
                                         smem + (buf) * 4096 + w * 512, 16, 0, 0);        \
        __builtin_amdgcn_global_load_lds(vg + (size_t)(kt_) * 4096,                       \
                                         smem + 12288 + (buf) * 4096 + w * 512, 16, 0, 0);\
    } while (0)

    const int NT = S_ / 64;   // 32
    FSTAGE(0, 0);
    FSTAGE(1, 1);

    int cur = 0;
    for (int kt = 0; kt < NT; kt++) {
        if (kt < NT - 1) asm volatile("s_waitcnt vmcnt(2)" ::: "memory");   // tile kt landed; kt+1 in flight
        else             asm volatile("s_waitcnt vmcnt(0)" ::: "memory");
        __builtin_amdgcn_s_barrier();       // everyone's tile kt visible; buf (kt+2)%3 free to overwrite
        __builtin_amdgcn_sched_barrier(0);
        if (kt + 2 < NT) {
            int nb2 = cur + 2; if (nb2 >= 3) nb2 -= 3;
            FSTAGE(nb2, kt + 2);
        }
        __builtin_amdgcn_sched_barrier(0);
        const uint16_t* Kc = smem + cur * 4096;
        const uint16_t* Vc = smem + 12288 + cur * 4096;

        // QK^T swapped; C-init = negm: sacc[nb] = s(kv = nb*16+4*lg+r, q = lr) - m
        f32x4 sacc[4];
        __builtin_amdgcn_s_setprio(1);
        #pragma unroll
        for (int nb = 0; nb < 4; nb++) {
            f16x8 kf = *(const f16x8*)(Kc + swz(nb * 16 + lr, 8 * lg));
            sacc[nb] = __builtin_amdgcn_mfma_f32_16x16x32_f16(kf, qf[0], negm, 0, 0, 0);
        }
        #pragma unroll
        for (int nb = 0; nb < 4; nb++) {
            f16x8 kf = *(const f16x8*)(Kc + swz(nb * 16 + lr, 32 + 8 * lg));
            sacc[nb] = __builtin_amdgcn_mfma_f32_16x16x32_f16(kf, qf[1], sacc[nb], 0, 0, 0);
        }
        __builtin_amdgcn_s_setprio(0);

        // per-lane max over own 16 scores (no cross-lane reduce on the fast path)
        float a0 = fmaxf(fmaxf(sacc[0][0], sacc[0][1]), sacc[0][2]);
        float a1 = fmaxf(fmaxf(sacc[0][3], sacc[1][0]), sacc[1][1]);
        float a2 = fmaxf(fmaxf(sacc[1][2], sacc[1][3]), sacc[2][0]);
        float a3 = fmaxf(fmaxf(sacc[2][1], sacc[2][2]), sacc[2][3]);
        float a4 = fmaxf(fmaxf(sacc[3][0], sacc[3][1]), sacc[3][2]);
        float pm = fmaxf(fmaxf(fmaxf(a0, a1), fmaxf(a2, a3)), fmaxf(a4, sacc[3][3]));

        // defer-max: rescale only when some row grew past m+11 (P <= 2^11 < f16 max)
        if (__any(pm > 11.0f)) {
            float tm = fmaxf(pm, __shfl_xor(pm, 16));
            tm = fmaxf(tm, __shfl_xor(tm, 32));
            float delta = fmaxf(tm, 0.0f);
            float sc = exp2f_fast(-delta);
            #pragma unroll
            for (int r = 0; r < 4; r++) negm[r] -= delta;
            #pragma unroll
            for (int nb = 0; nb < 4; nb++) {
                #pragma unroll
                for (int r = 0; r < 4; r++) sacc[nb][r] -= delta;
            }
            float scr[4];
            #pragma unroll
            for (int r = 0; r < 4; r++) scr[r] = __shfl(sc, 4 * lg + r);
            #pragma unroll
            for (int r = 0; r < 4; r++) lsum[r] *= scr[r];
            #pragma unroll
            for (int nb = 0; nb < 4; nb++) {
                #pragma unroll
                for (int r = 0; r < 4; r++) oacc[nb][r] *= scr[r];
            }
        }

        // P = exp2(sacc) packed (pkrtz) directly into PV A-fragments
        f16x8 paf[2];
        #pragma unroll
        for (int kb2 = 0; kb2 < 2; kb2++) {
            float e[8];
            #pragma unroll
            for (int jh = 0; jh < 2; jh++) {
                #pragma unroll
                for (int r = 0; r < 4; r++)
                    e[jh * 4 + r] = exp2f_fast(sacc[2 * kb2 + jh][r]);
            }
            uint4 u;
            u.x = pkrtz(e[0], e[1]); u.y = pkrtz(e[2], e[3]);
            u.z = pkrtz(e[4], e[5]); u.w = pkrtz(e[6], e[7]);
            paf[kb2] = __builtin_bit_cast(f16x8, u);
        }

        // l-sum via ones-MFMA (row sums land in oacc row layout) + PV
        __builtin_amdgcn_s_setprio(1);
        lsum = __builtin_amdgcn_mfma_f32_16x16x32_f16(paf[0], ones, lsum, 0, 0, 0);
        lsum = __builtin_amdgcn_mfma_f32_16x16x32_f16(paf[1], ones, lsum, 0, 0, 0);
        #pragma unroll
        for (int kb2 = 0; kb2 < 2; kb2++) {
            #pragma unroll
            for (int nb = 0; nb < 4; nb++) {
                f16x8 vf = *(const f16x8*)(Vc + ((kb2 * 4 + lg) * 64 + nb * 16 + lr) * 8);
                oacc[nb] = __builtin_amdgcn_mfma_f32_16x16x32_f16(paf[kb2], vf, oacc[nb], 0, 0, 0);
            }
        }
        __builtin_amdgcn_s_setprio(0);

        cur = (cur == 2) ? 0 : cur + 1;
    }
    #undef FSTAGE

    // normalize into LDS (reusing K/V space), then full-line coalesced stores
    __syncthreads();   // all waves done with K/V LDS
    float* outs = (float*)smem;   // 128 x 64 f32 = 32 KB
    #pragma unroll
    for (int r = 0; r < 4; r++) {
        const float inv = 1.0f / lsum[r];
        const int sl = w * 16 + 4 * lg + r;
        #pragma unroll
        for (int nb = 0; nb < 4; nb++)
            outs[sl * 64 + nb * 16 + lr] = oacc[nb][r] * inv;
    }
    __syncthreads();
    const int orow = t >> 4, oslot = t & 15;
    float* obase = out + (size_t)(b * S_ + qt * 128 + orow) * (H_ * A_) + h * A_ + oslot * 4;
    #pragma unroll
    for (int i = 0; i < 4; i++)
        *(float4*)(obase + (size_t)(32 * i) * (H_ * A_)) =
            *(const float4*)(outs + (orow + 32 * i) * 64 + oslot * 4);
}

// ----------------------------------------------------------------
extern "C" void kernel_launch(void* const* d_in, const int* in_sizes, int n_in,
                              void* d_out, int out_size, void* d_ws, size_t ws_size,
                              hipStream_t stream)
{
    const float* q  = (const float*)d_in[0];
    const float* k  = (const float*)d_in[1];
    const float* v  = (const float*)d_in[2];
    const float* Wq = (const float*)d_in[3];
    const float* bq = (const float*)d_in[4];
    const float* Wk = (const float*)d_in[5];
    const float* bk = (const float*)d_in[6];
    const float* Wv = (const float*)d_in[7];
    const float* bv = (const float*)d_in[8];
    float* out = (float*)d_out;

    uint8_t* ws = (uint8_t*)d_ws;
    const size_t SZ_H  = (size_t)BH_ * S_ * A_ * 2;     // 16 MB each
    uint16_t* qh  = (uint16_t*)(ws);
    uint16_t* kh  = (uint16_t*)(ws + SZ_H);
    uint16_t* vpv = (uint16_t*)(ws + 2 * SZ_H);
    uint16_t* Wt  = (uint16_t*)(ws + 3 * SZ_H);

    prep_w<<<dim3(16, H_, 3), 256, 0, stream>>>(Wq, Wk, Wv, Wt);
    proj_kernel<<<dim3(M_ / 128, 4, 3), 512, 0, stream>>>(q, k, v, Wt,
                                                          bq, bk, bv, qh, kh, vpv);
    flash_kernel<<<dim3(S_ / 128, BH_), 512, 0, stream>>>(qh, kh, vpv, out);
}